// Round 1
// baseline (156.375 us; speedup 1.0000x reference)
//
#include <hip/hip_runtime.h>

// Problem constants (match reference).
#define N_TOK   262144
#define D       256
#define NSEQ    512
#define MAX_LEN 640

#define CHUNK   256                  // rows per histogram/scatter block
#define NBLK    (N_TOK / CHUNK)      // 1024
#define SEG     16                   // chunks per scan segment
#define NSEGS   (NBLK / SEG)         // 64

// ---------------- Pass 1: per-chunk histogram ----------------
__global__ __launch_bounds__(256) void k_hist(const int* __restrict__ ids,
                                              int* __restrict__ counts) {
    __shared__ int h[NSEQ];
    const int b = blockIdx.x;
    for (int i = threadIdx.x; i < NSEQ; i += 256) h[i] = 0;
    __syncthreads();
    const int id = ids[b * CHUNK + threadIdx.x];
    atomicAdd(&h[id], 1);
    __syncthreads();
    for (int i = threadIdx.x; i < NSEQ; i += 256) counts[b * NSEQ + i] = h[i];
}

// ---------------- Pass 2a: per-segment sums ----------------
__global__ __launch_bounds__(512) void k_segsum(const int* __restrict__ counts,
                                                int* __restrict__ segsum) {
    const int seg = blockIdx.x;     // [0, NSEGS)
    const int s   = threadIdx.x;    // [0, NSEQ)
    int acc = 0;
#pragma unroll
    for (int k = 0; k < SEG; ++k) acc += counts[(seg * SEG + k) * NSEQ + s];
    segsum[seg * NSEQ + s] = acc;
}

// ---------------- Pass 2b: scan segments (1 block) ----------------
__global__ __launch_bounds__(512) void k_segscan(const int* __restrict__ segsum,
                                                 int* __restrict__ segpre,
                                                 int* __restrict__ totals) {
    const int s = threadIdx.x;      // [0, NSEQ)
    int acc = 0;
    for (int g = 0; g < NSEGS; ++g) {
        segpre[g * NSEQ + s] = acc;
        acc += segsum[g * NSEQ + s];
    }
    totals[s] = acc;
}

// ---------------- Pass 2c: expand to per-chunk prefix ----------------
__global__ __launch_bounds__(512) void k_expand(const int* __restrict__ counts,
                                                const int* __restrict__ segpre,
                                                int* __restrict__ prefix) {
    const int seg = blockIdx.x;
    const int s   = threadIdx.x;
    int acc = segpre[seg * NSEQ + s];
#pragma unroll
    for (int k = 0; k < SEG; ++k) {
        const int b = seg * SEG + k;
        prefix[b * NSEQ + s] = acc;
        acc += counts[b * NSEQ + s];
    }
}

// ---------------- Pass 3: within-chunk rank + scatter copy ----------------
__global__ __launch_bounds__(256) void k_scatter(const float* __restrict__ batch,
                                                 const int* __restrict__ ids,
                                                 const int* __restrict__ prefix,
                                                 float* __restrict__ padded) {
    __shared__ int lid[CHUNK];
    __shared__ int pre[NSEQ];
    __shared__ int drow[CHUNK];
    const int b = blockIdx.x;
    const int t = threadIdx.x;

    lid[t]       = ids[b * CHUNK + t];
    pre[t]       = prefix[b * NSEQ + t];
    pre[t + 256] = prefix[b * NSEQ + t + 256];
    __syncthreads();

    const int myid = lid[t];
    int r = 0;
    for (int j = 0; j < t; ++j) r += (lid[j] == myid);   // stable within-chunk rank
    r += pre[myid];
    drow[t] = (r < MAX_LEN) ? (myid * MAX_LEN + r) : -1; // drop OOB (JAX semantics)
    __syncthreads();

    // 4 waves; wave w copies rows [w*64, w*64+64). Each row = 1 KB = 64 lanes x float4.
    const int wave = t >> 6;
    const int lane = t & 63;
#pragma unroll 4
    for (int r2 = 0; r2 < 64; ++r2) {
        const int row = wave * 64 + r2;
        const int dr  = drow[row];
        if (dr < 0) continue;
        const float4* src = (const float4*)(batch + (size_t)(b * CHUNK + row) * D);
        float4*       dst = (float4*)(padded + (size_t)dr * D);
        dst[lane] = src[lane];
    }
}

// ---------------- Pass 4: zero-fill empty slots ----------------
__global__ __launch_bounds__(256) void k_zero(const int* __restrict__ totals,
                                              float* __restrict__ padded) {
    const int wid  = (blockIdx.x * 256 + threadIdx.x) >> 6;
    const int lane = threadIdx.x & 63;
    const int nw   = (gridDim.x * 256) >> 6;
    const float4 z = make_float4(0.f, 0.f, 0.f, 0.f);
    for (int slot = wid; slot < NSEQ * MAX_LEN; slot += nw) {
        const int s = slot / MAX_LEN;
        const int l = slot - s * MAX_LEN;
        if (l >= totals[s]) {
            ((float4*)(padded + (size_t)slot * D))[lane] = z;
        }
    }
}

// ---------------- Pass 5: padding mask (float 0/1) ----------------
__global__ __launch_bounds__(256) void k_mask(const int* __restrict__ totals,
                                              float* __restrict__ mask) {
    const int t = blockIdx.x * 256 + threadIdx.x;
    if (t >= NSEQ * MAX_LEN) return;
    const int s = t / MAX_LEN;
    const int l = t - s * MAX_LEN;
    mask[t] = (l >= totals[s]) ? 1.0f : 0.0f;
}

extern "C" void kernel_launch(void* const* d_in, const int* in_sizes, int n_in,
                              void* d_out, int out_size, void* d_ws, size_t ws_size,
                              hipStream_t stream) {
    const float* batch = (const float*)d_in[0];
    const int*   ids   = (const int*)d_in[1];

    float* padded = (float*)d_out;                               // [S, MAX_LEN, D]
    float* mask   = padded + (size_t)NSEQ * MAX_LEN * D;         // [S, MAX_LEN]

    int* ws      = (int*)d_ws;
    int* counts  = ws;                                // NBLK*NSEQ = 524288
    int* prefix  = counts + NBLK * NSEQ;              // NBLK*NSEQ
    int* segsum  = prefix + NBLK * NSEQ;              // NSEGS*NSEQ = 32768
    int* segpre  = segsum + NSEGS * NSEQ;             // NSEGS*NSEQ
    int* totals  = segpre + NSEGS * NSEQ;             // NSEQ
    // total ws use: ~4.46 MB

    k_hist   <<<NBLK,  256, 0, stream>>>(ids, counts);
    k_segsum <<<NSEGS, 512, 0, stream>>>(counts, segsum);
    k_segscan<<<1,     512, 0, stream>>>(segsum, segpre, totals);
    k_expand <<<NSEGS, 512, 0, stream>>>(counts, segpre, prefix);
    k_scatter<<<NBLK,  256, 0, stream>>>(batch, ids, prefix, padded);
    k_zero   <<<2048,  256, 0, stream>>>(totals, padded);
    k_mask   <<<(NSEQ * MAX_LEN + 255) / 256, 256, 0, stream>>>(totals, mask);
}

// Round 2
// 155.319 us; speedup vs baseline: 1.0068x; 1.0068x over previous
//
#include <hip/hip_runtime.h>

// Problem constants (match reference).
#define N_TOK   262144
#define D       256
#define NSEQ    512
#define MAX_LEN 640

#define CHUNK   256                  // rows per scatter block
#define NBLK    (N_TOK / CHUNK)      // 1024
#define SEG     16                   // chunks per scan segment
#define NSEGS   (NBLK / SEG)         // 64

// ---------------- Pass 1: fused per-chunk histogram + per-segment sum ----------
__global__ __launch_bounds__(512) void k_count(const int* __restrict__ ids,
                                               int* __restrict__ counts,
                                               int* __restrict__ segsum) {
    __shared__ int h[SEG][NSEQ];     // 32 KB
    const int seg = blockIdx.x;      // [0, NSEGS)
    const int t   = threadIdx.x;     // [0, 512)
#pragma unroll
    for (int k = 0; k < SEG; ++k) h[k][t] = 0;
    __syncthreads();
    const int base = seg * (SEG * CHUNK);   // 4096 ids per segment
#pragma unroll
    for (int k = 0; k < 8; ++k) {
        const int i  = t + 512 * k;         // [0, 4096)
        const int id = ids[base + i];
        atomicAdd(&h[i >> 8][id], 1);       // chunk-local histogram
    }
    __syncthreads();
    int acc = 0;
#pragma unroll
    for (int k = 0; k < SEG; ++k) {
        const int c = h[k][t];
        counts[(seg * SEG + k) * NSEQ + t] = c;
        acc += c;
    }
    segsum[seg * NSEQ + t] = acc;
}

// ---------------- Pass 2: per-chunk exclusive prefix + totals ----------------
// Block `seg` recomputes the scan over prior segments itself (removes the
// serial 1-block scan kernel); block NSEGS-1 also emits totals.
__global__ __launch_bounds__(512) void k_expand2(const int* __restrict__ counts,
                                                 const int* __restrict__ segsum,
                                                 int* __restrict__ prefix,
                                                 int* __restrict__ totals) {
    const int seg = blockIdx.x;
    const int t   = threadIdx.x;     // sequence id lane
    int acc = 0;
    for (int g = 0; g < seg; ++g) acc += segsum[g * NSEQ + t];
#pragma unroll
    for (int k = 0; k < SEG; ++k) {
        const int b = seg * SEG + k;
        prefix[b * NSEQ + t] = acc;
        acc += counts[b * NSEQ + t];
    }
    if (seg == NSEGS - 1) totals[t] = acc;
}

// ---------------- Pass 3: rank+scatter  ∥  zero-fill+mask ----------------
__global__ __launch_bounds__(256) void k_scatter_zero(const float* __restrict__ batch,
                                                      const int* __restrict__ ids,
                                                      const int* __restrict__ prefix,
                                                      const int* __restrict__ totals,
                                                      float* __restrict__ padded,
                                                      float* __restrict__ mask) {
    const int t = threadIdx.x;
    if (blockIdx.x < NBLK) {
        // ---- scatter: one 256-row chunk ----
        __shared__ int lid[CHUNK];
        __shared__ int pre[NSEQ];
        __shared__ int drow[CHUNK];
        const int b = blockIdx.x;

        lid[t]       = ids[b * CHUNK + t];
        pre[t]       = prefix[b * NSEQ + t];
        pre[t + 256] = prefix[b * NSEQ + t + 256];
        __syncthreads();

        const int myid = lid[t];
        int r = 0;
        for (int j = 0; j < t; ++j) r += (lid[j] == myid);  // stable in-chunk rank
        r += pre[myid];
        drow[t] = (r < MAX_LEN) ? (myid * MAX_LEN + r) : -1; // drop OOB (JAX semantics)
        __syncthreads();

        const int wave = t >> 6;
        const int lane = t & 63;
#pragma unroll 8
        for (int r2 = 0; r2 < 64; ++r2) {
            const int row = wave * 64 + r2;
            // batch row is always valid: load unconditionally so loads pipeline
            const float4 v =
                ((const float4*)(batch + (size_t)(b * CHUNK + row) * D))[lane];
            const int dr = drow[row];
            if (dr >= 0)
                ((float4*)(padded + (size_t)dr * D))[lane] = v;
        }
    } else {
        // ---- zero-fill empty slots + mask for one sequence ----
        const int s   = blockIdx.x - NBLK;   // [0, NSEQ)
        const int tot = totals[s];
        const int wave = t >> 6;
        const int lane = t & 63;
        const float4 z = make_float4(0.f, 0.f, 0.f, 0.f);
        for (int l = tot + wave; l < MAX_LEN; l += 4) {
            ((float4*)(padded + (size_t)(s * MAX_LEN + l) * D))[lane] = z;
        }
        for (int l = t; l < MAX_LEN; l += 256) {
            mask[s * MAX_LEN + l] = (l >= tot) ? 1.0f : 0.0f;
        }
    }
}

extern "C" void kernel_launch(void* const* d_in, const int* in_sizes, int n_in,
                              void* d_out, int out_size, void* d_ws, size_t ws_size,
                              hipStream_t stream) {
    const float* batch = (const float*)d_in[0];
    const int*   ids   = (const int*)d_in[1];

    float* padded = (float*)d_out;                        // [S, MAX_LEN, D]
    float* mask   = padded + (size_t)NSEQ * MAX_LEN * D;  // [S, MAX_LEN]

    int* ws     = (int*)d_ws;
    int* counts = ws;                       // NBLK*NSEQ
    int* prefix = counts + NBLK * NSEQ;     // NBLK*NSEQ
    int* segsum = prefix + NBLK * NSEQ;     // NSEGS*NSEQ
    int* totals = segsum + NSEGS * NSEQ;    // NSEQ
    // ws use ~4.3 MB (all fully rewritten every call before any read)

    k_count      <<<NSEGS,       512, 0, stream>>>(ids, counts, segsum);
    k_expand2    <<<NSEGS,       512, 0, stream>>>(counts, segsum, prefix, totals);
    k_scatter_zero<<<NBLK + NSEQ, 256, 0, stream>>>(batch, ids, prefix, totals,
                                                    padded, mask);
}